// Round 5
// baseline (579.262 us; speedup 1.0000x reference)
//
#include <hip/hip_runtime.h>
#include <cstdint>

#define NH 8
#define HD 96
#define CDIM 768
#define BQ 2
#define T0 8
#define H0 56
#define W0 56
#define L0 (T0*H0*W0)     // 25088
#define HP_Q 28
#define WP_Q 28
#define LQ (T0*HP_Q*WP_Q) // 6272
#define HP_K 7
#define WP_K 7
#define LK (T0*HP_K*WP_K) // 392
#define LKP 416           // kv padded to multiple of 32
#define SCALE 0.10206207261596577f

typedef __bf16 bf16;
typedef bf16 bf16x4 __attribute__((ext_vector_type(4)));
typedef bf16 bf16x8 __attribute__((ext_vector_type(8)));
typedef float f32x4 __attribute__((ext_vector_type(4)));
typedef float f4 __attribute__((ext_vector_type(4)));

#define GPTR(x) ((const __attribute__((address_space(1))) void*)(x))
#define LPTR(x) ((__attribute__((address_space(3))) void*)(x))

// fast erf-GELU: A&S 7.1.27 rational erf approx, |err(erf)| <= 5e-4 (<< bf16 rounding)
__device__ __forceinline__ float fast_gelu(float x) {
    float z = __builtin_fabsf(x) * 0.7071067811865476f;
    float p = 1.f + z*(0.278393f + z*(0.230389f + z*(0.000972f + z*0.078108f)));
    p = p * p;
    p = p * p;
    float e = 1.f - __builtin_amdgcn_rcpf(p);   // erf(|x|/sqrt2)
    float erfv = (x < 0.f) ? -e : e;
    return 0.5f * x * (1.f + erfv);
}

// ---------------- fp32 -> bf16 conversion ----------------
__global__ void cvt4(const f4* __restrict__ in, bf16x4* __restrict__ out, long n4) {
    long i = (long)blockIdx.x * blockDim.x + threadIdx.x;
    long stride = (long)gridDim.x * blockDim.x;
    for (; i < n4; i += stride) {
        f4 v = in[i];
        bf16x4 o;
        o.x = (bf16)v.x; o.y = (bf16)v.y; o.z = (bf16)v.z; o.w = (bf16)v.w;
        out[i] = o;
    }
}

// ---------------- MFMA GEMM: out[m,n] = sum_k A[m,k]*B[n,k] + bias[n] ----------------
// 1D grid, XCD-chunked bijective swizzle (m204), bn fastest within chunk.
// MODE 0: qkv. GELU applied iff col < gelu_cols. Scatter bf16 to
//         [part][b*NH+nh][L0][HD], part = col/768 (block-uniform; 768%128==0).
// MODE 1: proj. fp32 write to Out[m*N + n].
template<int MODE>
__global__ __launch_bounds__(256) void gemm_bt(
    const bf16* __restrict__ A, const bf16* __restrict__ B,
    const float* __restrict__ bias, void* __restrict__ Out,
    int M, int N, int K, int NBN, int gelu_cols)
{
    __shared__ bf16 As[128*32];
    __shared__ bf16 Bs[128*32];
    const int tid = threadIdx.x;
    const int lane = tid & 63;
    const int w = tid >> 6;
    const int wr = w >> 1, wc = w & 1;

    // XCD-aware bijective swizzle (T1, m204)
    const int nwg = gridDim.x;
    const int q_ = nwg >> 3, r_ = nwg & 7;
    const int xcd = blockIdx.x & 7, off = blockIdx.x >> 3;
    const int swz = (xcd < r_ ? xcd*(q_+1) : r_*(q_+1) + (xcd - r_)*q_) + off;
    const long bn = swz % NBN, bm = swz / NBN;

    f32x4 acc[4][4];
#pragma unroll
    for (int i = 0; i < 4; ++i)
#pragma unroll
        for (int j = 0; j < 4; ++j) acc[i][j] = (f32x4){0.f,0.f,0.f,0.f};

    const int lrow = tid >> 2;        // 0..63
    const int lcol = (tid & 3) * 8;   // 0,8,16,24
    const bf16* Ag = A + (bm*128 + lrow)*(long)K + lcol;
    const bf16* Bg = B + (bn*128 + lrow)*(long)K + lcol;
    bf16* As0 = &As[lrow*32 + lcol];   // = As + tid*16 bytes: linear for global_load_lds
    bf16* As1 = &As[(lrow+64)*32 + lcol];
    bf16* Bs0 = &Bs[lrow*32 + lcol];
    bf16* Bs1 = &Bs[(lrow+64)*32 + lcol];
    const int arow = lane & 15;
    const int akol = (lane >> 4) * 8;

    const int nkt = K / 32;
    for (int kt = 0; kt < nkt; ++kt) {
        __syncthreads();
        __builtin_amdgcn_global_load_lds(GPTR(Ag),          LPTR(As0), 16, 0, 0);
        __builtin_amdgcn_global_load_lds(GPTR(Ag + 64l*K),  LPTR(As1), 16, 0, 0);
        __builtin_amdgcn_global_load_lds(GPTR(Bg),          LPTR(Bs0), 16, 0, 0);
        __builtin_amdgcn_global_load_lds(GPTR(Bg + 64l*K),  LPTR(Bs1), 16, 0, 0);
        Ag += 32; Bg += 32;
        __syncthreads();
        bf16x8 af[4], bfr[4];
#pragma unroll
        for (int i = 0; i < 4; ++i) {
            af[i]  = *(const bf16x8*)&As[(wr*64 + i*16 + arow)*32 + akol];
            bfr[i] = *(const bf16x8*)&Bs[(wc*64 + i*16 + arow)*32 + akol];
        }
#pragma unroll
        for (int i = 0; i < 4; ++i)
#pragma unroll
            for (int j = 0; j < 4; ++j)
                acc[i][j] = __builtin_amdgcn_mfma_f32_16x16x32_bf16(af[i], bfr[j], acc[i][j], 0, 0, 0);
    }

    // epilogue: C/D layout col = lane&15, row = (lane>>4)*4 + r   [learn_hip m89]
#pragma unroll
    for (int j = 0; j < 4; ++j) {
        const int colb = (int)bn*128 + wc*64 + j*16;   // 16-lane-group base col
        const int col  = colb + (lane & 15);
        const float bcol = bias[col];
        const bool do_gelu = (MODE == 0) && (colb < gelu_cols);
        size_t pbase = 0;
        if (MODE == 0) {
            int part = colb / 768;                     // block-uniform
            int cb = colb - part*768;
            int nh = cb / HD;                          // group-uniform (never splits)
            int c = cb - nh*HD + (lane & 15);
            pbase = ((size_t)(part*16 + nh)) * (L0*HD) + c;
        }
#pragma unroll
        for (int i = 0; i < 4; ++i) {
            int row0 = (int)bm*128 + wr*64 + i*16 + ((lane>>4)<<2);
            size_t rbase = 0;
            if (MODE == 0) {
                int bflag = row0 >= L0;                // M = 2*L0; 4-row group never splits
                int l = row0 - (bflag ? L0 : 0);
                rbase = pbase + ((size_t)(bflag*8))*(L0*HD) + (size_t)l*HD;
            }
#pragma unroll
            for (int r = 0; r < 4; ++r) {
                float vacc = acc[i][j][r] + bcol;
                if (MODE == 0) {
                    float g = do_gelu ? fast_gelu(vacc) : vacc;
                    ((bf16*)Out)[rbase + (size_t)r*HD] = (bf16)g;
                } else {
                    ((float*)Out)[(size_t)(row0 + r)*N + col] = vacc;
                }
            }
        }
    }
}

// ---------------- depthwise conv3d (k=3, pad=1, stride (1,ST,ST)), bf16 out ----------
// thread = (bh, yo, xo, c8): computes all T0 'to' outputs for 8 channels.
// GELU_IN: apply GELU to loaded inputs (k/v path stores raw pre-activation).
// MODE 0: q -> out[bh][l][c];  MODE 1: k -> out[bh][l][c]; MODE 2: v -> out[bh][c][l]
template<int ST, int HP, int WP, int MODE, int LP, bool GELU_IN>
__global__ __launch_bounds__(256) void dwconv2(
    const bf16* __restrict__ in, const float* __restrict__ w,
    bf16* __restrict__ out, int total)
{
    __shared__ float lw[27*HD];
    for (int i = threadIdx.x; i < 27*HD; i += 256) {
        int c = i / 27, tap = i % 27;
        lw[tap*HD + c] = w[i];
    }
    __syncthreads();
    int idx = blockIdx.x*256 + threadIdx.x;
    if (idx >= total) return;         // total = 16*HP*WP*12
    int c8 = idx % 12;
    int p = idx / 12;
    int xo = p % WP;
    int yo = (p / WP) % HP;
    int bh = p / (WP*HP);
    const bf16* ip = in + (size_t)bh * L0 * HD + c8*8;

    float acc[T0][8];
#pragma unroll
    for (int t = 0; t < T0; ++t)
#pragma unroll
        for (int j = 0; j < 8; ++j) acc[t][j] = 0.f;

#pragma unroll
    for (int dy = 0; dy < 3; ++dy) {
        int y = yo*ST + dy - 1;
        if ((unsigned)y >= (unsigned)H0) continue;
#pragma unroll
        for (int dx = 0; dx < 3; ++dx) {
            int x = xo*ST + dx - 1;
            if ((unsigned)x >= (unsigned)W0) continue;
            float wreg[3][8];
#pragma unroll
            for (int dt = 0; dt < 3; ++dt)
#pragma unroll
                for (int j = 0; j < 8; ++j)
                    wreg[dt][j] = lw[(dt*9 + dy*3 + dx)*HD + c8*8 + j];
            const bf16* colp = ip + ((size_t)(y*W0 + x))*HD;
#pragma unroll
            for (int t = 0; t < T0; ++t) {
                bf16x8 v = *(const bf16x8*)(colp + (size_t)t*H0*W0*HD);
                float f[8];
#pragma unroll
                for (int j = 0; j < 8; ++j) {
                    f[j] = (float)v[j];
                    if (GELU_IN) f[j] = fast_gelu(f[j]);
                }
#pragma unroll
                for (int dt = 0; dt < 3; ++dt) {
                    int to = t - dt + 1;        // input t feeds outputs t-1,t,t+1
                    if (to < 0 || to >= T0) continue;
#pragma unroll
                    for (int j = 0; j < 8; ++j)
                        acc[to][j] += wreg[dt][j] * f[j];
                }
            }
        }
    }

#pragma unroll
    for (int to = 0; to < T0; ++to) {
        int l = (to*HP + yo)*WP + xo;
        if (MODE == 2) {
#pragma unroll
            for (int j = 0; j < 8; ++j)
                out[((size_t)bh*HD + c8*8 + j)*LP + l] = (bf16)acc[to][j];
        } else {
            bf16x8 ov;
#pragma unroll
            for (int j = 0; j < 8; ++j) ov[j] = (bf16)acc[to][j];
            *(bf16x8*)&out[((size_t)bh*LP + l)*HD + c8*8] = ov;
        }
    }
}

// ---------------- MFMA attention: block = (b,h) x 64 q rows, wave = 16 q rows -------
__global__ __launch_bounds__(256) void attn_mfma(
    const bf16* __restrict__ q, const bf16* __restrict__ k,
    const bf16* __restrict__ vt, bf16* __restrict__ out)
{
    const int tid = threadIdx.x;
    const int lane = tid & 63;
    const int w = tid >> 6;
    const int col = lane & 15;
    const int g = lane >> 4;
    const int blk = blockIdx.x;
    const int qblk = blk % (LQ/64);
    const int bh = blk / (LQ/64);
    const int q0 = qblk*64 + w*16;

    const bf16* Qp  = q  + ((size_t)bh*LQ + q0)*HD;
    const bf16* Kp  = k  + (size_t)bh*LKP*HD;
    const bf16* VTp = vt + (size_t)bh*HD*LKP;

    bf16x8 qf[3];
#pragma unroll
    for (int c = 0; c < 3; ++c)
        qf[c] = *(const bf16x8*)&Qp[(size_t)col*HD + c*32 + g*8];

    f32x4 o[6];
#pragma unroll
    for (int t = 0; t < 6; ++t) o[t] = (f32x4){0.f,0.f,0.f,0.f};
    float lsum = 0.f;

    for (int kc = 0; kc < LKP/32; ++kc) {
        const int kvb = kc*32;
        uint32_t P[2][2];
#pragma unroll
        for (int s = 0; s < 2; ++s) {
            f32x4 acc = (f32x4){0.f,0.f,0.f,0.f};
#pragma unroll
            for (int c = 0; c < 3; ++c) {
                bf16x8 kf = *(const bf16x8*)&Kp[(size_t)(kvb + s*16 + col)*HD + c*32 + g*8];
                acc = __builtin_amdgcn_mfma_f32_16x16x32_bf16(kf, qf[c], acc, 0, 0, 0);
            }
            bf16x4 pb;
#pragma unroll
            for (int r = 0; r < 4; ++r) {
                int kv = kvb + s*16 + g*4 + r;
                float p = (kv < LK) ? __expf(acc[r]*SCALE) : 0.f;
                lsum += p;
                pb[r] = (bf16)p;
            }
            union { bf16x4 v; uint32_t u[2]; } pk; pk.v = pb;
            P[s][0] = pk.u[0]; P[s][1] = pk.u[1];
        }
        uint32_t sa0 = (g < 2) ? P[1][0] : P[0][0];
        uint32_t sa1 = (g < 2) ? P[1][1] : P[0][1];
        uint32_t tb0 = (g < 2) ? P[0][0] : P[1][0];
        uint32_t tb1 = (g < 2) ? P[0][1] : P[1][1];
        uint32_t R32_0 = (uint32_t)__shfl_xor((int)sa0, 32);
        uint32_t R32_1 = (uint32_t)__shfl_xor((int)sa1, 32);
        uint32_t R48_0 = (uint32_t)__shfl_xor((int)sa0, 48);
        uint32_t R48_1 = (uint32_t)__shfl_xor((int)sa1, 48);
        uint32_t R16_0 = (uint32_t)__shfl_xor((int)tb0, 16);
        uint32_t R16_1 = (uint32_t)__shfl_xor((int)tb1, 16);
        union { uint32_t u[4]; bf16x8 v; } pf;
        pf.u[0] = (g == 0) ? P[0][0] : (g == 1) ? R48_0 : (g == 2) ? R32_0 : R16_0;
        pf.u[1] = (g == 0) ? P[0][1] : (g == 1) ? R48_1 : (g == 2) ? R32_1 : R16_1;
        pf.u[2] = (g == 0) ? R16_0 : (g == 1) ? R32_0 : (g == 2) ? R48_0 : P[1][0];
        pf.u[3] = (g == 0) ? R16_1 : (g == 1) ? R32_1 : (g == 2) ? R48_1 : P[1][1];
#pragma unroll
        for (int t = 0; t < 6; ++t) {
            bf16x8 vf = *(const bf16x8*)&VTp[(size_t)(t*16 + col)*LKP + kvb + g*8];
            o[t] = __builtin_amdgcn_mfma_f32_16x16x32_bf16(vf, pf.v, o[t], 0, 0, 0);
        }
    }

    lsum += __shfl_xor(lsum, 16);
    lsum += __shfl_xor(lsum, 32);
    float inv = 1.f / lsum;

    const int b = bh >> 3, nh = bh & 7;
    size_t obase = ((size_t)b*LQ + q0 + col)*CDIM + (size_t)nh*HD;
#pragma unroll
    for (int t = 0; t < 6; ++t) {
        bf16x4 qres = *(const bf16x4*)&Qp[(size_t)col*HD + t*16 + g*4];
        bf16x4 ov;
#pragma unroll
        for (int r = 0; r < 4; ++r)
            ov[r] = (bf16)(o[t][r]*inv + (float)qres[r]);
        *(bf16x4*)&out[obase + t*16 + g*4] = ov;
    }
}

extern "C" void kernel_launch(void* const* d_in, const int* in_sizes, int n_in,
                              void* d_out, int out_size, void* d_ws, size_t ws_size,
                              hipStream_t stream) {
    const float* x      = (const float*)d_in[0];
    const float* qkv_w  = (const float*)d_in[1];
    const float* qkv_b  = (const float*)d_in[2];
    const float* proj_w = (const float*)d_in[3];
    const float* proj_b = (const float*)d_in[4];
    const float* pq_w   = (const float*)d_in[5];
    const float* pk_w   = (const float*)d_in[6];
    const float* pv_w   = (const float*)d_in[7];

    uint8_t* ws = (uint8_t*)d_ws;
    const bool fused = ws_size >= 355000000ull;

    bf16 *x_bf, *qkv_g, *wqkv_bf, *wproj_bf, *q_bf, *k_bf, *vt_bf, *attn_o;
    x_bf = (bf16*)ws;                              // 77,070,336 B
    if (fused) {
        qkv_g    = (bf16*)(ws +  77070336);        // 231,211,008 B: [3][16][L0][96]
        wqkv_bf  = (bf16*)(ws + 308281344);        // 3,538,944 B
        wproj_bf = (bf16*)(ws + 311820288);        // 1,179,648 B
        q_bf     = (bf16*)(ws + 312999936);        // 19,267,584 B [16][6272][96]
        k_bf     = (bf16*)(ws + 332267520);        // 1,277,952 B  [16][416][96]
        vt_bf    = (bf16*)(ws + 333545472);        // 1,277,952 B  [16][96][416]
        attn_o   = (bf16*)(ws + 334823424);        // 19,267,584 B -> end 354,091,008
    } else {
        qkv_g    = (bf16*)(ws +  77070336);        // 77,070,336 B (one part at a time)
        wqkv_bf  = (bf16*)(ws + 154140672);
        wproj_bf = (bf16*)(ws + 157679616);
        q_bf     = (bf16*)(ws + 158859264);
        k_bf     = (bf16*)(ws + 178126848);
        vt_bf    = (bf16*)(ws + 179404800);
        attn_o   = (bf16*)(ws + 180682752);        // -> end 199,950,336
    }

    hipMemsetAsync(k_bf, 0, 1277952, stream);
    hipMemsetAsync(vt_bf, 0, 1277952, stream);

    cvt4<<<2048, 256, 0, stream>>>((const f4*)x, (bf16x4*)x_bf, 38535168/4);
    cvt4<<<1728, 256, 0, stream>>>((const f4*)qkv_w, (bf16x4*)wqkv_bf, 1769472/4);
    cvt4<<<576, 256, 0, stream>>>((const f4*)proj_w, (bf16x4*)wproj_bf, 589824/4);

    const size_t PART = (size_t)16*L0*HD;
    if (fused) {
        // qkv GEMM: M=50176, N=2304, K=768. GELU only on Q cols (<768); K/V stored raw.
        gemm_bt<0><<<18*392, 256, 0, stream>>>(
            x_bf, wqkv_bf, qkv_b, qkv_g, 50176, 2304, 768, 18, 768);
        dwconv2<2, HP_Q, WP_Q, 0, LQ, false><<<588, 256, 0, stream>>>(
            qkv_g, pq_w, q_bf, 16*HP_Q*WP_Q*12);
        dwconv2<8, HP_K, WP_K, 1, LKP, true><<<37, 256, 0, stream>>>(
            qkv_g + PART, pk_w, k_bf, 16*HP_K*WP_K*12);
        dwconv2<8, HP_K, WP_K, 2, LKP, true><<<37, 256, 0, stream>>>(
            qkv_g + 2*PART, pv_w, vt_bf, 16*HP_K*WP_K*12);
    } else {
        for (int p = 0; p < 3; ++p) {
            gemm_bt<0><<<6*392, 256, 0, stream>>>(
                x_bf, wqkv_bf + (size_t)p*768*768, qkv_b + p*768, qkv_g,
                50176, 768, 768, 6, p == 0 ? 768 : 0);
            if (p == 0)
                dwconv2<2, HP_Q, WP_Q, 0, LQ, false><<<588, 256, 0, stream>>>(
                    qkv_g, pq_w, q_bf, 16*HP_Q*WP_Q*12);
            else if (p == 1)
                dwconv2<8, HP_K, WP_K, 1, LKP, true><<<37, 256, 0, stream>>>(
                    qkv_g, pk_w, k_bf, 16*HP_K*WP_K*12);
            else
                dwconv2<8, HP_K, WP_K, 2, LKP, true><<<37, 256, 0, stream>>>(
                    qkv_g, pv_w, vt_bf, 16*HP_K*WP_K*12);
        }
    }

    attn_mfma<<<16*(LQ/64), 256, 0, stream>>>(q_bf, k_bf, vt_bf, attn_o);

    gemm_bt<1><<<6*98, 256, 0, stream>>>(
        attn_o, wproj_bf, proj_b, d_out, 12544, 768, 768, 6, 0);
}

// Round 6
// 505.355 us; speedup vs baseline: 1.1462x; 1.1462x over previous
//
#include <hip/hip_runtime.h>
#include <cstdint>

#define NH 8
#define HD 96
#define CDIM 768
#define BQ 2
#define T0 8
#define H0 56
#define W0 56
#define L0 (T0*H0*W0)     // 25088
#define HP_Q 28
#define WP_Q 28
#define LQ (T0*HP_Q*WP_Q) // 6272
#define HP_K 7
#define WP_K 7
#define LK (T0*HP_K*WP_K) // 392
#define LKP 416           // kv padded to multiple of 32
#define SCALE 0.10206207261596577f

typedef __bf16 bf16;
typedef bf16 bf16x4 __attribute__((ext_vector_type(4)));
typedef bf16 bf16x8 __attribute__((ext_vector_type(8)));
typedef float f32x4 __attribute__((ext_vector_type(4)));
typedef float f4 __attribute__((ext_vector_type(4)));

#define GPTR(x) ((const __attribute__((address_space(1))) void*)(x))
#define LPTR(x) ((__attribute__((address_space(3))) void*)(x))

// fast erf-GELU: A&S 7.1.27 rational erf approx, |err(erf)| <= 5e-4 (<< bf16 rounding)
__device__ __forceinline__ float fast_gelu(float x) {
    float z = __builtin_fabsf(x) * 0.7071067811865476f;
    float p = 1.f + z*(0.278393f + z*(0.230389f + z*(0.000972f + z*0.078108f)));
    p = p * p;
    p = p * p;
    float e = 1.f - __builtin_amdgcn_rcpf(p);   // erf(|x|/sqrt2)
    float erfv = (x < 0.f) ? -e : e;
    return 0.5f * x * (1.f + erfv);
}

// ---------------- fp32 -> bf16 conversion ----------------
__global__ void cvt4(const f4* __restrict__ in, bf16x4* __restrict__ out, long n4) {
    long i = (long)blockIdx.x * blockDim.x + threadIdx.x;
    long stride = (long)gridDim.x * blockDim.x;
    for (; i < n4; i += stride) {
        f4 v = in[i];
        bf16x4 o;
        o.x = (bf16)v.x; o.y = (bf16)v.y; o.z = (bf16)v.z; o.w = (bf16)v.w;
        out[i] = o;
    }
}

// ---------------- MFMA GEMM: out[m,n] = sum_k A[m,k]*B[n,k] + bias[n] ----------------
// 128x128 tile, BK=64, dbuf LDS, 2-phase pipeline w/ counted vmcnt + raw barriers,
// T2 XOR-swizzled LDS (inverse-swizzled global src, swizzled ds_read).
// 1D grid, XCD-chunked bijective swizzle (m204), bn fastest within chunk.
// MODE 0: qkv. GELU iff col < gelu_cols. LDS-transpose epilogue, bf16x8 stores to
//         [part][b*NH+nh][L0][HD].
// MODE 1: proj. direct fp32 stores Out[m*N + n].
template<int MODE>
__global__ __launch_bounds__(256) void gemm_bt(
    const bf16* __restrict__ A, const bf16* __restrict__ B,
    const float* __restrict__ bias, void* __restrict__ Out,
    int M, int N, int K, int NBN, int gelu_cols)
{
    __shared__ bf16 sh[2*16384];     // [buf][A:8192|B:8192] elements = 64 KiB
    const int tid = threadIdx.x;
    const int lane = tid & 63;
    const int w = tid >> 6;
    const int wr = w >> 1, wc = w & 1;

    // XCD-aware bijective swizzle (T1, m204)
    const int nwg = gridDim.x;
    const int q_ = nwg >> 3, r_ = nwg & 7;
    const int xcd = blockIdx.x & 7, off = blockIdx.x >> 3;
    const int swz = (xcd < r_ ? xcd*(q_+1) : r_*(q_+1) + (xcd - r_)*q_) + off;
    const long bn = swz % NBN, bm = swz / NBN;

    f32x4 acc[4][4];
#pragma unroll
    for (int i = 0; i < 4; ++i)
#pragma unroll
        for (int j = 0; j < 4; ++j) acc[i][j] = (f32x4){0.f,0.f,0.f,0.f};

    // staging: thread t covers (row = s*32 + t>>3, src chunk = (t&7)^((t>>3)&7))
    const int trow = tid >> 3;                       // 0..31
    const int tchunk = (tid & 7) ^ (trow & 7);       // inverse swizzle (involution)
    const bf16* Ag = A + (bm*128 + trow)*(long)K + tchunk*8;
    const bf16* Bg = B + (bn*128 + trow)*(long)K + tchunk*8;

    const int arow = lane & 15;
    const int g8 = (lane >> 4) * 8;
    const int aswz = (arow & 7) * 8;                 // element-XOR for ds_read

    auto stage = [&](int buf, int kt) {
        const bf16* Asrc = Ag + (long)kt*64;
        const bf16* Bsrc = Bg + (long)kt*64;
        bf16* ldsA = sh + buf*16384;
        bf16* ldsB = sh + buf*16384 + 8192;
#pragma unroll
        for (int s = 0; s < 4; ++s) {
            __builtin_amdgcn_global_load_lds(GPTR(Asrc + (long)s*32*K), LPTR(ldsA + s*2048 + tid*8), 16, 0, 0);
            __builtin_amdgcn_global_load_lds(GPTR(Bsrc + (long)s*32*K), LPTR(ldsB + s*2048 + tid*8), 16, 0, 0);
        }
    };
    auto compute = [&](int buf) {
        const bf16* ldsA = sh + buf*16384;
        const bf16* ldsB = sh + buf*16384 + 8192;
#pragma unroll
        for (int kk = 0; kk < 2; ++kk) {
            bf16x8 af[4], bfr[4];
#pragma unroll
            for (int i = 0; i < 4; ++i)
                af[i] = *(const bf16x8*)&ldsA[(wr*64 + i*16 + arow)*64 + ((kk*32 + g8) ^ aswz)];
#pragma unroll
            for (int j = 0; j < 4; ++j)
                bfr[j] = *(const bf16x8*)&ldsB[(wc*64 + j*16 + arow)*64 + ((kk*32 + g8) ^ aswz)];
#pragma unroll
            for (int i = 0; i < 4; ++i)
#pragma unroll
                for (int j = 0; j < 4; ++j)
                    acc[i][j] = __builtin_amdgcn_mfma_f32_16x16x32_bf16(af[i], bfr[j], acc[i][j], 0, 0, 0);
        }
    };

    const int nkt = K / 64;
    stage(0, 0);
    for (int kt = 0; kt < nkt; ++kt) {
        if (kt + 1 < nkt) {
            stage((kt + 1) & 1, kt + 1);
            asm volatile("s_waitcnt vmcnt(8)" ::: "memory");   // kt's 8 loads landed
        } else {
            asm volatile("s_waitcnt vmcnt(0)" ::: "memory");
        }
        __builtin_amdgcn_s_barrier();
        __builtin_amdgcn_sched_barrier(0);
        compute(kt & 1);
        __builtin_amdgcn_sched_barrier(0);
        __builtin_amdgcn_s_barrier();
    }

    // ---------------- epilogue ----------------
    if (MODE == 1) {
#pragma unroll
        for (int j = 0; j < 4; ++j) {
            const int col = (int)bn*128 + wc*64 + j*16 + (lane & 15);
            const float bcol = bias[col];
#pragma unroll
            for (int i = 0; i < 4; ++i) {
                int row0 = (int)bm*128 + wr*64 + i*16 + ((lane>>4)<<2);
#pragma unroll
                for (int r = 0; r < 4; ++r)
                    ((float*)Out)[(size_t)(row0 + r)*N + col] = acc[i][j][r] + bcol;
            }
        }
    } else {
        // stage tile into LDS (bf16, padded 136 cols), then coalesced bf16x8 stores
        bf16* tls = sh;                       // 128*136*2 = 34816 B <= 64 KiB
#pragma unroll
        for (int j = 0; j < 4; ++j) {
            const int colb = (int)bn*128 + wc*64 + j*16;
            const int lcol = wc*64 + j*16 + (lane & 15);
            const float bcol = bias[colb + (lane & 15)];
            const bool do_gelu = colb < gelu_cols;
#pragma unroll
            for (int i = 0; i < 4; ++i) {
                int lrow0 = wr*64 + i*16 + ((lane>>4)<<2);
#pragma unroll
                for (int r = 0; r < 4; ++r) {
                    float vacc = acc[i][j][r] + bcol;
                    if (do_gelu) vacc = fast_gelu(vacc);
                    tls[(lrow0 + r)*136 + lcol] = (bf16)vacc;
                }
            }
        }
        __syncthreads();
#pragma unroll
        for (int it = 0; it < 8; ++it) {
            int idx = it*256 + tid;           // 0..2047
            int mloc = idx >> 4;              // 0..127
            int ck = idx & 15;                // 16-byte chunk
            bf16x8 v = *(const bf16x8*)&tls[mloc*136 + ck*8];
            int m = (int)bm*128 + mloc;
            int col = (int)bn*128 + ck*8;
            int part = col / 768;
            int cb = col - part*768;
            int nh = cb / HD;
            int c = cb - nh*HD;
            int bflag = m >= L0;              // M = 2*L0
            int l = m - (bflag ? L0 : 0);
            size_t addr = ((size_t)(part*16 + bflag*8 + nh)*L0 + l)*HD + c;
            *(bf16x8*)&((bf16*)Out)[addr] = v;
        }
    }
}

// ---------------- depthwise conv3d (k=3, pad=1, stride (1,ST,ST)), bf16 out ----------
// thread = (bh, yo, xo, c8): computes all T0 'to' outputs for 8 channels.
// GELU_IN: apply GELU to loaded inputs (k/v path stores raw pre-activation).
// MODE 0: q -> out[bh][l][c];  MODE 1: k -> out[bh][l][c]; MODE 2: v -> out[bh][c][l]
template<int ST, int HP, int WP, int MODE, int LP, bool GELU_IN>
__global__ __launch_bounds__(256) void dwconv2(
    const bf16* __restrict__ in, const float* __restrict__ w,
    bf16* __restrict__ out, int total)
{
    __shared__ float lw[27*HD];
    for (int i = threadIdx.x; i < 27*HD; i += 256) {
        int c = i / 27, tap = i % 27;
        lw[tap*HD + c] = w[i];
    }
    __syncthreads();
    int idx = blockIdx.x*256 + threadIdx.x;
    if (idx >= total) return;         // total = 16*HP*WP*12
    int c8 = idx % 12;
    int p = idx / 12;
    int xo = p % WP;
    int yo = (p / WP) % HP;
    int bh = p / (WP*HP);
    const bf16* ip = in + (size_t)bh * L0 * HD + c8*8;

    float acc[T0][8];
#pragma unroll
    for (int t = 0; t < T0; ++t)
#pragma unroll
        for (int j = 0; j < 8; ++j) acc[t][j] = 0.f;

#pragma unroll
    for (int dy = 0; dy < 3; ++dy) {
        int y = yo*ST + dy - 1;
        if ((unsigned)y >= (unsigned)H0) continue;
#pragma unroll
        for (int dx = 0; dx < 3; ++dx) {
            int x = xo*ST + dx - 1;
            if ((unsigned)x >= (unsigned)W0) continue;
            float wreg[3][8];
#pragma unroll
            for (int dt = 0; dt < 3; ++dt)
#pragma unroll
                for (int j = 0; j < 8; ++j)
                    wreg[dt][j] = lw[(dt*9 + dy*3 + dx)*HD + c8*8 + j];
            const bf16* colp = ip + ((size_t)(y*W0 + x))*HD;
#pragma unroll
            for (int t = 0; t < T0; ++t) {
                bf16x8 v = *(const bf16x8*)(colp + (size_t)t*H0*W0*HD);
                float f[8];
#pragma unroll
                for (int j = 0; j < 8; ++j) {
                    f[j] = (float)v[j];
                    if (GELU_IN) f[j] = fast_gelu(f[j]);
                }
#pragma unroll
                for (int dt = 0; dt < 3; ++dt) {
                    int to = t - dt + 1;        // input t feeds outputs t-1,t,t+1
                    if (to < 0 || to >= T0) continue;
#pragma unroll
                    for (int j = 0; j < 8; ++j)
                        acc[to][j] += wreg[dt][j] * f[j];
                }
            }
        }
    }

#pragma unroll
    for (int to = 0; to < T0; ++to) {
        int l = (to*HP + yo)*WP + xo;
        if (MODE == 2) {
#pragma unroll
            for (int j = 0; j < 8; ++j)
                out[((size_t)bh*HD + c8*8 + j)*LP + l] = (bf16)acc[to][j];
        } else {
            bf16x8 ov;
#pragma unroll
            for (int j = 0; j < 8; ++j) ov[j] = (bf16)acc[to][j];
            *(bf16x8*)&out[((size_t)bh*LP + l)*HD + c8*8] = ov;
        }
    }
}

// ---------------- MFMA attention: block = (b,h) x 64 q rows, wave = 16 q rows -------
__global__ __launch_bounds__(256) void attn_mfma(
    const bf16* __restrict__ q, const bf16* __restrict__ k,
    const bf16* __restrict__ vt, bf16* __restrict__ out)
{
    const int tid = threadIdx.x;
    const int lane = tid & 63;
    const int w = tid >> 6;
    const int col = lane & 15;
    const int g = lane >> 4;
    const int blk = blockIdx.x;
    const int qblk = blk % (LQ/64);
    const int bh = blk / (LQ/64);
    const int q0 = qblk*64 + w*16;

    const bf16* Qp  = q  + ((size_t)bh*LQ + q0)*HD;
    const bf16* Kp  = k  + (size_t)bh*LKP*HD;
    const bf16* VTp = vt + (size_t)bh*HD*LKP;

    bf16x8 qf[3];
#pragma unroll
    for (int c = 0; c < 3; ++c)
        qf[c] = *(const bf16x8*)&Qp[(size_t)col*HD + c*32 + g*8];

    f32x4 o[6];
#pragma unroll
    for (int t = 0; t < 6; ++t) o[t] = (f32x4){0.f,0.f,0.f,0.f};
    float lsum = 0.f;

    for (int kc = 0; kc < LKP/32; ++kc) {
        const int kvb = kc*32;
        uint32_t P[2][2];
#pragma unroll
        for (int s = 0; s < 2; ++s) {
            f32x4 acc = (f32x4){0.f,0.f,0.f,0.f};
#pragma unroll
            for (int c = 0; c < 3; ++c) {
                bf16x8 kf = *(const bf16x8*)&Kp[(size_t)(kvb + s*16 + col)*HD + c*32 + g*8];
                acc = __builtin_amdgcn_mfma_f32_16x16x32_bf16(kf, qf[c], acc, 0, 0, 0);
            }
            bf16x4 pb;
#pragma unroll
            for (int r = 0; r < 4; ++r) {
                int kv = kvb + s*16 + g*4 + r;
                float p = (kv < LK) ? __expf(acc[r]*SCALE) : 0.f;
                lsum += p;
                pb[r] = (bf16)p;
            }
            union { bf16x4 v; uint32_t u[2]; } pk; pk.v = pb;
            P[s][0] = pk.u[0]; P[s][1] = pk.u[1];
        }
        uint32_t sa0 = (g < 2) ? P[1][0] : P[0][0];
        uint32_t sa1 = (g < 2) ? P[1][1] : P[0][1];
        uint32_t tb0 = (g < 2) ? P[0][0] : P[1][0];
        uint32_t tb1 = (g < 2) ? P[0][1] : P[1][1];
        uint32_t R32_0 = (uint32_t)__shfl_xor((int)sa0, 32);
        uint32_t R32_1 = (uint32_t)__shfl_xor((int)sa1, 32);
        uint32_t R48_0 = (uint32_t)__shfl_xor((int)sa0, 48);
        uint32_t R48_1 = (uint32_t)__shfl_xor((int)sa1, 48);
        uint32_t R16_0 = (uint32_t)__shfl_xor((int)tb0, 16);
        uint32_t R16_1 = (uint32_t)__shfl_xor((int)tb1, 16);
        union { uint32_t u[4]; bf16x8 v; } pf;
        pf.u[0] = (g == 0) ? P[0][0] : (g == 1) ? R48_0 : (g == 2) ? R32_0 : R16_0;
        pf.u[1] = (g == 0) ? P[0][1] : (g == 1) ? R48_1 : (g == 2) ? R32_1 : R16_1;
        pf.u[2] = (g == 0) ? R16_0 : (g == 1) ? R32_0 : (g == 2) ? R48_0 : P[1][0];
        pf.u[3] = (g == 0) ? R16_1 : (g == 1) ? R32_1 : (g == 2) ? R48_1 : P[1][1];
#pragma unroll
        for (int t = 0; t < 6; ++t) {
            bf16x8 vf = *(const bf16x8*)&VTp[(size_t)(t*16 + col)*LKP + kvb + g*8];
            o[t] = __builtin_amdgcn_mfma_f32_16x16x32_bf16(vf, pf.v, o[t], 0, 0, 0);
        }
    }

    lsum += __shfl_xor(lsum, 16);
    lsum += __shfl_xor(lsum, 32);
    float inv = 1.f / lsum;

    const int b = bh >> 3, nh = bh & 7;
    size_t obase = ((size_t)b*LQ + q0 + col)*CDIM + (size_t)nh*HD;
#pragma unroll
    for (int t = 0; t < 6; ++t) {
        bf16x4 qres = *(const bf16x4*)&Qp[(size_t)col*HD + t*16 + g*4];
        bf16x4 ov;
#pragma unroll
        for (int r = 0; r < 4; ++r)
            ov[r] = (bf16)(o[t][r]*inv + (float)qres[r]);
        *(bf16x4*)&out[obase + t*16 + g*4] = ov;
    }
}

extern "C" void kernel_launch(void* const* d_in, const int* in_sizes, int n_in,
                              void* d_out, int out_size, void* d_ws, size_t ws_size,
                              hipStream_t stream) {
    const float* x      = (const float*)d_in[0];
    const float* qkv_w  = (const float*)d_in[1];
    const float* qkv_b  = (const float*)d_in[2];
    const float* proj_w = (const float*)d_in[3];
    const float* proj_b = (const float*)d_in[4];
    const float* pq_w   = (const float*)d_in[5];
    const float* pk_w   = (const float*)d_in[6];
    const float* pv_w   = (const float*)d_in[7];

    uint8_t* ws = (uint8_t*)d_ws;
    const bool fused = ws_size >= 355000000ull;

    bf16 *x_bf, *qkv_g, *wqkv_bf, *wproj_bf, *q_bf, *k_bf, *vt_bf, *attn_o;
    x_bf = (bf16*)ws;                              // 77,070,336 B
    if (fused) {
        qkv_g    = (bf16*)(ws +  77070336);        // 231,211,008 B: [3][16][L0][96]
        wqkv_bf  = (bf16*)(ws + 308281344);        // 3,538,944 B
        wproj_bf = (bf16*)(ws + 311820288);        // 1,179,648 B
        q_bf     = (bf16*)(ws + 312999936);        // 19,267,584 B [16][6272][96]
        k_bf     = (bf16*)(ws + 332267520);        // 1,277,952 B  [16][416][96]
        vt_bf    = (bf16*)(ws + 333545472);        // 1,277,952 B  [16][96][416]
        attn_o   = (bf16*)(ws + 334823424);        // 19,267,584 B -> end 354,091,008
    } else {
        qkv_g    = (bf16*)(ws +  77070336);        // 77,070,336 B (one part at a time)
        wqkv_bf  = (bf16*)(ws + 154140672);
        wproj_bf = (bf16*)(ws + 157679616);
        q_bf     = (bf16*)(ws + 158859264);
        k_bf     = (bf16*)(ws + 178126848);
        vt_bf    = (bf16*)(ws + 179404800);
        attn_o   = (bf16*)(ws + 180682752);        // -> end 199,950,336
    }

    hipMemsetAsync(k_bf, 0, 1277952, stream);
    hipMemsetAsync(vt_bf, 0, 1277952, stream);

    cvt4<<<2048, 256, 0, stream>>>((const f4*)x, (bf16x4*)x_bf, 38535168/4);
    cvt4<<<1728, 256, 0, stream>>>((const f4*)qkv_w, (bf16x4*)wqkv_bf, 1769472/4);
    cvt4<<<576, 256, 0, stream>>>((const f4*)proj_w, (bf16x4*)wproj_bf, 589824/4);

    const size_t PART = (size_t)16*L0*HD;
    if (fused) {
        // qkv GEMM: M=50176, N=2304, K=768. GELU only on Q cols (<768); K/V stored raw.
        gemm_bt<0><<<18*392, 256, 0, stream>>>(
            x_bf, wqkv_bf, qkv_b, qkv_g, 50176, 2304, 768, 18, 768);
        dwconv2<2, HP_Q, WP_Q, 0, LQ, false><<<588, 256, 0, stream>>>(
            qkv_g, pq_w, q_bf, 16*HP_Q*WP_Q*12);
        dwconv2<8, HP_K, WP_K, 1, LKP, true><<<37, 256, 0, stream>>>(
            qkv_g + PART, pk_w, k_bf, 16*HP_K*WP_K*12);
        dwconv2<8, HP_K, WP_K, 2, LKP, true><<<37, 256, 0, stream>>>(
            qkv_g + 2*PART, pv_w, vt_bf, 16*HP_K*WP_K*12);
    } else {
        for (int p = 0; p < 3; ++p) {
            gemm_bt<0><<<6*392, 256, 0, stream>>>(
                x_bf, wqkv_bf + (size_t)p*768*768, qkv_b + p*768, qkv_g,
                50176, 768, 768, 6, p == 0 ? 768 : 0);
            if (p == 0)
                dwconv2<2, HP_Q, WP_Q, 0, LQ, false><<<588, 256, 0, stream>>>(
                    qkv_g, pq_w, q_bf, 16*HP_Q*WP_Q*12);
            else if (p == 1)
                dwconv2<8, HP_K, WP_K, 1, LKP, true><<<37, 256, 0, stream>>>(
                    qkv_g, pk_w, k_bf, 16*HP_K*WP_K*12);
            else
                dwconv2<8, HP_K, WP_K, 2, LKP, true><<<37, 256, 0, stream>>>(
                    qkv_g, pv_w, vt_bf, 16*HP_K*WP_K*12);
        }
    }

    attn_mfma<<<16*(LQ/64), 256, 0, stream>>>(q_bf, k_bf, vt_bf, attn_o);

    gemm_bt<1><<<6*98, 256, 0, stream>>>(
        attn_o, wproj_bf, proj_b, d_out, 12544, 768, 768, 6, 0);
}